// Round 15
// baseline (3870.947 us; speedup 1.0000x reference)
//
#include <hip/hip_runtime.h>
#include <hip/hip_bf16.h>

#define L_SEQ 1024
#define D_MODEL 768
#define D_INNER 1536
#define D_STATE 16
#define DT_RANK 48
#define N_LAYERS 24
#define NCHUNK 16
#define CS (L_SEQ / NCHUNK)  // 64
#define KSPLIT_OUT 4
#define RDS_CN 64

typedef __attribute__((ext_vector_type(8))) short short8;
typedef __attribute__((ext_vector_type(4))) float f32x4;

// fp32 -> bf16 round-to-nearest-even
__device__ inline ushort rtn1(float v) {
  unsigned b = __float_as_uint(v);
  return (ushort)((b + 0x7FFF + ((b >> 16) & 1)) >> 16);
}

__device__ inline void gload16(const void* g, void* l) {
  __builtin_amdgcn_global_load_lds(
      (const __attribute__((address_space(1))) void*)g,
      (__attribute__((address_space(3))) void*)l, 16, 0, 0);
}

// ---------------------------------------------------------------------------
// transpose + bf16(RTN): in [K][N] fp32 (layer l) -> [N][Kp] bf16.
// rows k >= K zero-padded. grid (N/64, Kp/64, L) x 256. Packed uint stores.
__global__ __launch_bounds__(256) void tsplit_k(
    const float* __restrict__ in, ushort* __restrict__ hi, int K, int N,
    int Kp) {
  __shared__ float tile[64][65];
  const int l = blockIdx.z;
  const float* src = in + (size_t)l * K * N;
  ushort* dh = hi + (size_t)l * N * Kp;
  const int n0 = blockIdx.x * 64, k0 = blockIdx.y * 64;
  const int tx = threadIdx.x & 63, ty = threadIdx.x >> 6;
#pragma unroll
  for (int rr = 0; rr < 16; rr++) {
    int ky = rr * 4 + ty;
    int k = k0 + ky;
    tile[ky][tx] = (k < K) ? src[(size_t)k * N + n0 + tx] : 0.f;
  }
  __syncthreads();
  const int txk = threadIdx.x & 31;  // k-pair 0..31
  const int tyn = threadIdx.x >> 5;  // n 0..7
#pragma unroll
  for (int rr = 0; rr < 8; rr++) {
    int ny = rr * 8 + tyn;
    unsigned p = (unsigned)rtn1(tile[2 * txk][ny]) |
                 ((unsigned)rtn1(tile[2 * txk + 1][ny]) << 16);
    *(unsigned*)&dh[(size_t)(n0 + ny) * Kp + k0 + 2 * txk] = p;
  }
}

// ---------------------------------------------------------------------------
// 1-pass bf16 MFMA GEMM, double-buffered global_load_lds staging with
// counted vmcnt (prefetch stays in flight across barriers). XOR swizzle.
// A [M][lda] bf16, B [N][ldb] bf16 (transposed weights). C fp32 [M][ldc].
// K % 32 == 0, M % 128 == 0, N % 64 == 0. block = 256 thr = 4 waves;
// tile BM=128 x BN=64, wave tile 64x32, BK=32, LDS 2x12 KB.
// gridDim.z slices K (partials at C + z*M*ldc; caller reduces).
__global__ __launch_bounds__(256) void gemm_bf16(
    const ushort* __restrict__ A, int lda, const ushort* __restrict__ B,
    int ldb, float* __restrict__ C, int ldc, int K) {
  __shared__ ushort lds[2][192 * 32];

  const int tid = threadIdx.x;
  const int bm = blockIdx.y * 128;
  const int bn = blockIdx.x * 64;
  const int kz0 = blockIdx.z * K;
  const int lane = tid & 63;
  const int wid = tid >> 6;
  const int wm = wid & 1, wn = wid >> 1;
  const int r = lane & 15, g = lane >> 4;
  const int segrow = lane >> 2;
  const int segch = lane & 3;

  auto stage = [&](int buf, int k0) {
#pragma unroll
    for (int i = 0; i < 3; i++) {
      int s = wid * 3 + i;
      int gr = s * 16 + segrow;
      int rt = gr & 63;
      int ch = segch ^ ((rt >> 1) & 3);
      bool isA = gr < 128;
      const ushort* src = isA ? A : B;
      int row = isA ? (bm + gr) : (bn + gr - 128);
      int ld = isA ? lda : ldb;
      gload16(src + (size_t)row * ld + k0 + ch * 8, &lds[buf][s * 512]);
    }
  };

  f32x4 acc[4][2] = {};
  const int nt = K / 32;

  stage(0, kz0);

  for (int t = 0; t < nt; t++) {
    const int cur = t & 1;
    if (t + 1 < nt) {
      stage(cur ^ 1, kz0 + (t + 1) * 32);
      asm volatile("s_waitcnt vmcnt(3)" ::: "memory");
    } else {
      asm volatile("s_waitcnt vmcnt(0)" ::: "memory");
    }
    __builtin_amdgcn_s_barrier();
    __builtin_amdgcn_sched_barrier(0);

    short8 af[4], bf[2];
#pragma unroll
    for (int m = 0; m < 4; m++) {
      int row = wm * 64 + m * 16 + r;
      int gg = g ^ ((row >> 1) & 3);
      af[m] = *reinterpret_cast<short8*>(&lds[cur][row * 32 + gg * 8]);
    }
#pragma unroll
    for (int n = 0; n < 2; n++) {
      int row = wn * 32 + n * 16 + r;
      int gg = g ^ ((row >> 1) & 3);
      bf[n] = *reinterpret_cast<short8*>(&lds[cur][(128 + row) * 32 + gg * 8]);
    }
#pragma unroll
    for (int m = 0; m < 4; m++)
#pragma unroll
      for (int n = 0; n < 2; n++)
        acc[m][n] = __builtin_amdgcn_mfma_f32_16x16x32_bf16(
            af[m], bf[n], acc[m][n], 0, 0, 0);
    __builtin_amdgcn_s_barrier();
  }

  float* Cz = C + (size_t)blockIdx.z * gridDim.y * 128 * ldc;
#pragma unroll
  for (int m = 0; m < 4; m++) {
#pragma unroll
    for (int n = 0; n < 2; n++) {
      int row0 = bm + wm * 64 + m * 16 + g * 4;
      int col = bn + wn * 32 + n * 16 + r;
#pragma unroll
      for (int j = 0; j < 4; j++)
        Cz[(size_t)(row0 + j) * ldc + col] = acc[m][n][j];
    }
  }
}

// ---------------------------------------------------------------------------
__global__ __launch_bounds__(256) void encode_k(
    const float* __restrict__ x, const float* __restrict__ w_enc,
    const float* __restrict__ b_enc, float* __restrict__ u) {
  int d = blockIdx.x * 256 + threadIdx.x;
  int t = blockIdx.y;
  const float4 xv = *(const float4*)(x + t * 4);
  float acc = b_enc[d];
  acc = fmaf(xv.x, w_enc[0 * D_MODEL + d], acc);
  acc = fmaf(xv.y, w_enc[1 * D_MODEL + d], acc);
  acc = fmaf(xv.z, w_enc[2 * D_MODEL + d], acc);
  acc = fmaf(xv.w, w_enc[3 * D_MODEL + d], acc);
  u[t * D_MODEL + d] = acc;
}

// ---------------------------------------------------------------------------
// layer-0 rmsnorm -> bf16
__global__ __launch_bounds__(256) void rmsnorm_b_k(
    const float* __restrict__ u, const float* __restrict__ w,
    ushort* __restrict__ hb) {
  int t = blockIdx.x;
  const float* ur = u + t * D_MODEL;
  float ss = 0.f;
  float vl[3];
#pragma unroll
  for (int p = 0; p < 3; p++) {
    int d = threadIdx.x + p * 256;
    vl[p] = ur[d];
    ss = fmaf(vl[p], vl[p], ss);
  }
#pragma unroll
  for (int o = 1; o < 64; o <<= 1) ss += __shfl_xor(ss, o);
  __shared__ float red[4];
  int wid = threadIdx.x >> 6;
  if ((threadIdx.x & 63) == 0) red[wid] = ss;
  __syncthreads();
  float rs = rsqrtf((red[0] + red[1] + red[2] + red[3]) / (float)D_MODEL +
                    1e-5f);
#pragma unroll
  for (int p = 0; p < 3; p++) {
    int d = threadIdx.x + p * 256;
    hb[t * D_MODEL + d] = rtn1(vl[p] * rs * w[d]);
  }
}

// rmsnorm fused with residual accumulation of prev layer's split-K partials
__global__ __launch_bounds__(256) void rmsnorm_add_k(
    const float* __restrict__ Po, float* __restrict__ u,
    const float* __restrict__ w, ushort* __restrict__ hb) {
  int t = blockIdx.x;
  float* ur = u + t * D_MODEL;
  float ss = 0.f;
  float vl[3];
#pragma unroll
  for (int p = 0; p < 3; p++) {
    int d = threadIdx.x + p * 256;
    float v = ur[d];
#pragma unroll
    for (int z = 0; z < KSPLIT_OUT; z++)
      v += Po[(size_t)z * L_SEQ * D_MODEL + (size_t)t * D_MODEL + d];
    ur[d] = v;
    vl[p] = v;
    ss = fmaf(v, v, ss);
  }
#pragma unroll
  for (int o = 1; o < 64; o <<= 1) ss += __shfl_xor(ss, o);
  __shared__ float red[4];
  int wid = threadIdx.x >> 6;
  if ((threadIdx.x & 63) == 0) red[wid] = ss;
  __syncthreads();
  float rs = rsqrtf((red[0] + red[1] + red[2] + red[3]) / (float)D_MODEL +
                    1e-5f);
#pragma unroll
  for (int p = 0; p < 3; p++) {
    int d = threadIdx.x + p * 256;
    hb[t * D_MODEL + d] = rtn1(vl[p] * rs * w[d]);
  }
}

// ---------------------------------------------------------------------------
// dbl GEMM (M=1024, N=80, K=1536) split-K fp32 partials, conv+silu fused
// into A-staging. T14 issue-early pipeline. (round-10 proven version)
#define DBL_NS 8
#define DBL_KSEG (D_INNER / DBL_NS)  // 192
__global__ __launch_bounds__(256) void gemm_dblconv_k(
    const float* __restrict__ xz, const float* __restrict__ cw,
    const float* __restrict__ cb, const float* __restrict__ B,
    float* __restrict__ P, float* __restrict__ xc) {
  __shared__ float As2[16][17];
  __shared__ float Bs2[16][80];
  const int tid = threadIdx.x;
  const int bm = blockIdx.y * 16;
  const int ks0 = blockIdx.x * DBL_KSEG;
  const int tx = tid % 16;
  const int ty = tid / 16;
  const int sm = tid / 16, sk = tid % 16;
  const int t = bm + sm;

  float4 wv;
  float cbv, xv0, xv1, xv2, xv3, bv0, bv1, bv2, bv3, bv4;
  auto issue = [&](int k0) {
    int c = k0 + sk;
    wv = *(const float4*)(cw + c * 4);
    cbv = cb[c];
    xv0 = (t >= 3) ? xz[(size_t)(t - 3) * 2 * D_INNER + c] : 0.f;
    xv1 = (t >= 2) ? xz[(size_t)(t - 2) * 2 * D_INNER + c] : 0.f;
    xv2 = (t >= 1) ? xz[(size_t)(t - 1) * 2 * D_INNER + c] : 0.f;
    xv3 = xz[(size_t)t * 2 * D_INNER + c];
    bv0 = B[(size_t)(k0 + (tid + 0) / 80) * 80 + (tid + 0) % 80];
    bv1 = B[(size_t)(k0 + (tid + 256) / 80) * 80 + (tid + 256) % 80];
    bv2 = B[(size_t)(k0 + (tid + 512) / 80) * 80 + (tid + 512) % 80];
    bv3 = B[(size_t)(k0 + (tid + 768) / 80) * 80 + (tid + 768) % 80];
    bv4 = B[(size_t)(k0 + (tid + 1024) / 80) * 80 + (tid + 1024) % 80];
  };

  float acc[5] = {0.f, 0.f, 0.f, 0.f, 0.f};

  issue(ks0);

  for (int k0 = ks0; k0 < ks0 + DBL_KSEG; k0 += 16) {
    float a = cbv;
    a = fmaf(xv0, wv.x, a);
    a = fmaf(xv1, wv.y, a);
    a = fmaf(xv2, wv.z, a);
    a = fmaf(xv3, wv.w, a);
    float v = a / (1.f + __expf(-a));
    xc[(size_t)t * D_INNER + k0 + sk] = v;
    As2[sk][sm] = v;
    Bs2[(tid + 0) / 80][(tid + 0) % 80] = bv0;
    Bs2[(tid + 256) / 80][(tid + 256) % 80] = bv1;
    Bs2[(tid + 512) / 80][(tid + 512) % 80] = bv2;
    Bs2[(tid + 768) / 80][(tid + 768) % 80] = bv3;
    Bs2[(tid + 1024) / 80][(tid + 1024) % 80] = bv4;
    if (k0 + 16 < ks0 + DBL_KSEG) issue(k0 + 16);
    asm volatile("s_waitcnt lgkmcnt(0)" ::: "memory");
    __builtin_amdgcn_s_barrier();
    __builtin_amdgcn_sched_barrier(0);
#pragma unroll
    for (int k = 0; k < 16; k++) {
      float ra = As2[k][ty];
#pragma unroll
      for (int j = 0; j < 5; j++) acc[j] = fmaf(ra, Bs2[k][tx * 5 + j], acc[j]);
    }
    __builtin_amdgcn_s_barrier();
  }

  float* p = P + ((size_t)blockIdx.x * L_SEQ + bm + ty) * 80 + tx * 5;
#pragma unroll
  for (int j = 0; j < 5; j++) p[j] = acc[j];
}

// ---------------------------------------------------------------------------
// FUSED: reduce dbl split-K partials + dt=softplus(dbl[:,:48]@dt_w+b) +
// scan phase 1, per (channel-slice, chunk) tile so dt/B/xc stay in LDS.
// grid (D_INNER/RDS_CN=24, NCHUNK=16) = 384 blocks x 256 thr, ~62 KB LDS.
// Writes: dtb, dbl cols 48..79 (slice 0 only), Pb, Eb. All fp32 orderings
// identical to the separate reduce_dt_k + scan1_k.
__global__ __launch_bounds__(256) void rds_k(
    const float* __restrict__ P, const float* __restrict__ dtw,
    const float* __restrict__ dtbias, const float* __restrict__ xc,
    const float* __restrict__ A_log, float* __restrict__ dbl,
    float* __restrict__ dtb, float* __restrict__ Pb,
    float* __restrict__ Eb) {
  __shared__ float s_dbl[CS][49];          // reduced cols 0..47 (+pad)
  __shared__ float s_b[CS][16];            // reduced cols 48..63 (B)
  __shared__ float wch[DT_RANK][RDS_CN + 1];
  __shared__ float s_dt[CS][RDS_CN];
  __shared__ float s_xc[CS][RDS_CN];

  const int tid = threadIdx.x;
  const int cc = blockIdx.x * RDS_CN;  // channel slice base
  const int t0 = blockIdx.y * CS;      // chunk base

  // A: reduce the 8 partials for this chunk's 64 rows (ks order preserved)
  for (int i = tid; i < CS * 80; i += 256) {
    int rr = i / 80, col = i % 80;
    float s = 0.f;
#pragma unroll
    for (int ks = 0; ks < DBL_NS; ks++)
      s += P[((size_t)ks * L_SEQ + t0 + rr) * 80 + col];
    if (col < DT_RANK)
      s_dbl[rr][col] = s;
    else if (col < 64)
      s_b[rr][col - DT_RANK] = s;
    if (blockIdx.x == 0 && col >= DT_RANK)
      dbl[(size_t)(t0 + rr) * 80 + col] = s;
  }
  // A2: dt_w slice [48][64]
  for (int i = tid; i < DT_RANK * RDS_CN; i += 256)
    wch[i / RDS_CN][i % RDS_CN] =
        dtw[(size_t)(i / RDS_CN) * D_INNER + cc + (i % RDS_CN)];
  // A3: xc tile [64 rows][64 ch] (coalesced)
  for (int i = tid; i < CS * RDS_CN; i += 256)
    s_xc[i / RDS_CN][i % RDS_CN] =
        xc[(size_t)(t0 + i / RDS_CN) * D_INNER + cc + (i % RDS_CN)];
  __syncthreads();

  // B: dt for 64 rows x 64 channels (same fma order as reduce_dt_k)
  {
    const int colB = tid & 63;
    const int row0 = tid >> 6;  // 0..3
    float bias = dtbias[cc + colB];
#pragma unroll
    for (int i = 0; i < CS / 4; i++) {
      int r = row0 + i * 4;
      float s = bias;
#pragma unroll
      for (int j = 0; j < DT_RANK; j++) s = fmaf(s_dbl[r][j], wch[j][colB], s);
      float sp = (s > 20.f) ? s : log1pf(__expf(s));
      s_dt[r][colB] = sp;
      dtb[(size_t)(t0 + r) * D_INNER + cc + colB] = sp;
    }
  }
  __syncthreads();

  // C: scan phase 1 for the 4 channel-subgroups (identical per-(c,s) math)
  const int s = tid & 15;
  const int cl = tid >> 4;
#pragma unroll
  for (int sg = 0; sg < 4; sg++) {
    int chl = sg * 16 + cl;
    int c = cc + chl;
    float a = -__expf(A_log[c * D_STATE + s]);
    float Pp = 1.f, h = 0.f;
    for (int t = 0; t < CS; t++) {
      float dtv = s_dt[t][chl];
      float dA = __expf(dtv * a);
      Pp *= dA;
      h = fmaf(dA, h, dtv * s_b[t][s] * s_xc[t][chl]);
    }
    int idx = blockIdx.y * (D_INNER * D_STATE) + (cc + sg * 16) * D_STATE + tid;
    Pb[idx] = Pp;
    Eb[idx] = h;
  }
}

// ---------------------------------------------------------------------------
// phase 3 (+ inline chunk combine) -> y bf16 (RTN)
__global__ __launch_bounds__(256) void scan3_k(
    const float* __restrict__ dt, const float* __restrict__ xc,
    const float* __restrict__ dbl, const float* __restrict__ xz,
    const float* __restrict__ A_log, const float* __restrict__ D_skip,
    const float* __restrict__ Pb, const float* __restrict__ Eb,
    ushort* __restrict__ yb16) {
  __shared__ float s_dt[CS][16];
  __shared__ float s_xc[CS][16];
  __shared__ float s_z[CS][16];
  __shared__ float s_bc[CS][32];

  const int tid = threadIdx.x;
  const int s = tid & 15;
  const int cl = tid >> 4;
  const int c0 = blockIdx.y * 16;
  const int c = c0 + cl;
  const int t0 = blockIdx.x * CS;

  const float a = -__expf(A_log[c * D_STATE + s]);
  const float Dv = D_skip[c];

  const int lc = tid & 15, lt = tid >> 4;
  const int bj = tid & 31, bt = tid >> 5;
#pragma unroll
  for (int p = 0; p < CS / 16; p++) {
    int t = lt + p * 16;
    size_t gt = (size_t)(t0 + t);
    s_dt[t][lc] = dt[gt * D_INNER + c0 + lc];
    s_xc[t][lc] = xc[gt * D_INNER + c0 + lc];
    s_z[t][lc] = xz[gt * 2 * D_INNER + D_INNER + c0 + lc];
  }
#pragma unroll
  for (int p = 0; p < CS / 8; p++) {
    int t = bt + p * 8;
    s_bc[t][bj] = dbl[(size_t)(t0 + t) * 80 + DT_RANK + bj];
  }

  // inline chunk combine: start state for this chunk (static indices)
  float hst = 0.f;
  {
    const int nj = blockIdx.x;
    const int base = c0 * D_STATE + tid;
    float pj[NCHUNK - 1], ej[NCHUNK - 1];
#pragma unroll
    for (int jj = 0; jj < NCHUNK - 1; jj++) {
      if (jj < nj) {
        int o = jj * (D_INNER * D_STATE) + base;
        pj[jj] = Pb[o];
        ej[jj] = Eb[o];
      }
    }
#pragma unroll
    for (int jj = 0; jj < NCHUNK - 1; jj++)
      if (jj < nj) hst = fmaf(pj[jj], hst, ej[jj]);
  }
  __syncthreads();

  for (int t = 0; t < CS; t++) {
    float dtv = s_dt[t][cl];
    float xv = s_xc[t][cl];
    float Bv = s_bc[t][s];
    float Cv = s_bc[t][16 + s];
    float dA = __expf(dtv * a);
    hst = fmaf(dA, hst, dtv * Bv * xv);
    float p2 = hst * Cv;
    p2 += __shfl_xor(p2, 1);
    p2 += __shfl_xor(p2, 2);
    p2 += __shfl_xor(p2, 4);
    p2 += __shfl_xor(p2, 8);
    if (s == 0) {
      float zv = s_z[t][cl];
      float sz = zv / (1.f + __expf(-zv));
      yb16[(size_t)(t0 + t) * D_INNER + c] = rtn1((p2 + Dv * xv) * sz);
    }
  }
}

// ---------------------------------------------------------------------------
// final: u[1023] += sum_z Po[z][1023]; rmsnorm; @ fc_w + fc_b
__global__ __launch_bounds__(256) void final_k(
    const float* __restrict__ u, const float* __restrict__ Po,
    const float* __restrict__ nfw, const float* __restrict__ fcw,
    const float* __restrict__ fcb, float* __restrict__ out) {
  const float* ur = u + (size_t)(L_SEQ - 1) * D_MODEL;
  float ss = 0.f;
  float vl[3];
#pragma unroll
  for (int p = 0; p < 3; p++) {
    int d = threadIdx.x + p * 256;
    float v = ur[d];
#pragma unroll
    for (int z = 0; z < KSPLIT_OUT; z++)
      v += Po[(size_t)z * L_SEQ * D_MODEL + (size_t)(L_SEQ - 1) * D_MODEL + d];
    vl[p] = v;
    ss = fmaf(v, v, ss);
  }
#pragma unroll
  for (int o = 1; o < 64; o <<= 1) ss += __shfl_xor(ss, o);
  __shared__ float red[4];
  int wid = threadIdx.x >> 6;
  if ((threadIdx.x & 63) == 0) red[wid] = ss;
  __syncthreads();
  float rs = rsqrtf((red[0] + red[1] + red[2] + red[3]) / (float)D_MODEL +
                    1e-5f);
  float a0 = 0.f, a1 = 0.f;
#pragma unroll
  for (int p = 0; p < 3; p++) {
    int d = threadIdx.x + p * 256;
    float hn = vl[p] * rs * nfw[d];
    a0 = fmaf(hn, fcw[d * 2 + 0], a0);
    a1 = fmaf(hn, fcw[d * 2 + 1], a1);
  }
#pragma unroll
  for (int o = 1; o < 64; o <<= 1) {
    a0 += __shfl_xor(a0, o);
    a1 += __shfl_xor(a1, o);
  }
  __shared__ float r0[4], r1[4];
  if ((threadIdx.x & 63) == 0) {
    r0[wid] = a0;
    r1[wid] = a1;
  }
  __syncthreads();
  if (threadIdx.x == 0) out[0] = r0[0] + r0[1] + r0[2] + r0[3] + fcb[0];
  if (threadIdx.x == 1) out[1] = r1[0] + r1[1] + r1[2] + r1[3] + fcb[1];
}

// ---------------------------------------------------------------------------
extern "C" void kernel_launch(void* const* d_in, const int* in_sizes, int n_in,
                              void* d_out, int out_size, void* d_ws,
                              size_t ws_size, hipStream_t stream) {
  const float* x      = (const float*)d_in[0];
  const float* w_enc  = (const float*)d_in[1];
  const float* b_enc  = (const float*)d_in[2];
  const float* norm_w = (const float*)d_in[3];
  const float* in_w   = (const float*)d_in[4];
  const float* conv_w = (const float*)d_in[5];
  const float* conv_b = (const float*)d_in[6];
  const float* xp_w   = (const float*)d_in[7];
  const float* dt_w   = (const float*)d_in[8];
  const float* dt_b   = (const float*)d_in[9];
  const float* A_log  = (const float*)d_in[10];
  const float* D_skip = (const float*)d_in[11];
  const float* out_w  = (const float*)d_in[12];
  const float* nf_w   = (const float*)d_in[13];
  const float* fc_w   = (const float*)d_in[14];
  const float* fc_b   = (const float*)d_in[15];
  float* out = (float*)d_out;

  // ---- fp32 workspace
  float* u   = (float*)d_ws;
  float* xzb = u   + (size_t)L_SEQ * D_MODEL;
  float* xcb = xzb + (size_t)L_SEQ * 2 * D_INNER;
  float* dbl = xcb + (size_t)L_SEQ * D_INNER;
  float* dtb = dbl + (size_t)L_SEQ * 80;
  float* yb  = dtb + (size_t)L_SEQ * D_INNER;      // dbl split-K partials
  float* Po  = yb  + (size_t)L_SEQ * 80 * DBL_NS;  // out split-K partials x4
  float* Pb  = Po  + (size_t)KSPLIT_OUT * L_SEQ * D_MODEL;
  float* Eb  = Pb  + (size_t)NCHUNK * D_INNER * D_STATE;
  float* fend = Eb + (size_t)NCHUNK * D_INNER * D_STATE;

  // ---- bf16 workspace (activations + repacked weights)
  ushort* hb   = (ushort*)fend;                 // [1024][768]
  ushort* yb16 = hb + (size_t)L_SEQ * D_MODEL;  // [1024][1536]
  ushort* wxT  = yb16 + (size_t)L_SEQ * D_INNER;  // in_w^T  [24][3072][768]
  ushort* woT  = wxT + (size_t)N_LAYERS * 2 * D_INNER * D_MODEL;  // [24][768][1536]

  // ---- one-time per call: weight repack (transpose + bf16 RTN)
  tsplit_k<<<dim3(2 * D_INNER / 64, D_MODEL / 64, N_LAYERS), 256, 0, stream>>>(
      in_w, wxT, D_MODEL, 2 * D_INNER, D_MODEL);
  tsplit_k<<<dim3(D_MODEL / 64, D_INNER / 64, N_LAYERS), 256, 0, stream>>>(
      out_w, woT, D_INNER, D_MODEL, D_INNER);

  encode_k<<<dim3(3, L_SEQ), 256, 0, stream>>>(x, w_enc, b_enc, u);

  for (int l = 0; l < N_LAYERS; l++) {
    const float* cw_l    = conv_w + (size_t)l * D_INNER * 4;
    const float* cb_l    = conv_b + (size_t)l * D_INNER;
    const float* xp_w_l  = xp_w  + (size_t)l * D_INNER * 80;
    const float* dt_w_l  = dt_w  + (size_t)l * DT_RANK * D_INNER;
    const float* dt_b_l  = dt_b  + (size_t)l * D_INNER;
    const float* A_log_l = A_log + (size_t)l * D_INNER * D_STATE;
    const float* D_l     = D_skip + (size_t)l * D_INNER;
    const ushort* wxT_l = wxT + (size_t)l * 2 * D_INNER * D_MODEL;
    const ushort* woT_l = woT + (size_t)l * D_MODEL * D_INNER;

    // h = bf16(rmsnorm(u [+ prev-layer out partials]) * norm_w)
    if (l == 0) {
      rmsnorm_b_k<<<L_SEQ, 256, 0, stream>>>(
          u, norm_w + (size_t)l * D_MODEL, hb);
    } else {
      rmsnorm_add_k<<<L_SEQ, 256, 0, stream>>>(
          Po, u, norm_w + (size_t)l * D_MODEL, hb);
    }
    // xz = h @ in_w : M=1024 N=3072 K=768 (384 blocks)
    gemm_bf16<<<dim3(2 * D_INNER / 64, L_SEQ / 128), 256, 0, stream>>>(
        hb, D_MODEL, wxT_l, D_MODEL, xzb, 2 * D_INNER, D_MODEL);
    // xc = silu(conv(xpart)+cb) fused into dbl split-K GEMM (512 blocks)
    gemm_dblconv_k<<<dim3(DBL_NS, L_SEQ / 16), 256, 0, stream>>>(
        xzb, cw_l, cb_l, xp_w_l, yb, xcb);
    // fused reduce + dt + scan1 (384 blocks, 64ch x 64t tiles)
    rds_k<<<dim3(D_INNER / RDS_CN, NCHUNK), 256, 0, stream>>>(
        yb, dt_w_l, dt_b_l, xcb, A_log_l, dbl, dtb, Pb, Eb);
    // scan phase 3 + skip + silu(z) gate -> y bf16
    scan3_k<<<dim3(NCHUNK, D_INNER / 16), 256, 0, stream>>>(
        dtb, xcb, dbl, xzb, A_log_l, D_l, Pb, Eb, yb16);
    // Po[z] = y @ out_w slices : M=1024 N=768, split-K x4 (384 blocks)
    gemm_bf16<<<dim3(D_MODEL / 64, L_SEQ / 128, KSPLIT_OUT), 256, 0,
                stream>>>(yb16, D_INNER, woT_l, D_INNER, Po, D_MODEL,
                          D_INNER / KSPLIT_OUT);
    // u-update deferred into next layer's rmsnorm_add / final_k
  }

  final_k<<<1, 256, 0, stream>>>(u, Po, nf_w, fc_w, fc_b, out);
}

// Round 16
// 2676.874 us; speedup vs baseline: 1.4461x; 1.4461x over previous
//
#include <hip/hip_runtime.h>
#include <hip/hip_bf16.h>

#define L_SEQ 1024
#define D_MODEL 768
#define D_INNER 1536
#define D_STATE 16
#define DT_RANK 48
#define N_LAYERS 24
#define NCHUNK 16
#define CS (L_SEQ / NCHUNK)  // 64
#define KSPLIT_OUT 4

typedef __attribute__((ext_vector_type(8))) short short8;
typedef __attribute__((ext_vector_type(4))) float f32x4;

// fp32 -> bf16 round-to-nearest-even
__device__ inline ushort rtn1(float v) {
  unsigned b = __float_as_uint(v);
  return (ushort)((b + 0x7FFF + ((b >> 16) & 1)) >> 16);
}

__device__ inline void gload16(const void* g, void* l) {
  __builtin_amdgcn_global_load_lds(
      (const __attribute__((address_space(1))) void*)g,
      (__attribute__((address_space(3))) void*)l, 16, 0, 0);
}

// ---------------------------------------------------------------------------
// transpose + bf16(RTN): in [K][N] fp32 (layer l) -> [N][Kp] bf16.
// rows k >= K zero-padded. grid (N/64, Kp/64, L) x 256. Packed uint stores.
__global__ __launch_bounds__(256) void tsplit_k(
    const float* __restrict__ in, ushort* __restrict__ hi, int K, int N,
    int Kp) {
  __shared__ float tile[64][65];
  const int l = blockIdx.z;
  const float* src = in + (size_t)l * K * N;
  ushort* dh = hi + (size_t)l * N * Kp;
  const int n0 = blockIdx.x * 64, k0 = blockIdx.y * 64;
  const int tx = threadIdx.x & 63, ty = threadIdx.x >> 6;
#pragma unroll
  for (int rr = 0; rr < 16; rr++) {
    int ky = rr * 4 + ty;
    int k = k0 + ky;
    tile[ky][tx] = (k < K) ? src[(size_t)k * N + n0 + tx] : 0.f;
  }
  __syncthreads();
  const int txk = threadIdx.x & 31;  // k-pair 0..31
  const int tyn = threadIdx.x >> 5;  // n 0..7
#pragma unroll
  for (int rr = 0; rr < 8; rr++) {
    int ny = rr * 8 + tyn;
    unsigned p = (unsigned)rtn1(tile[2 * txk][ny]) |
                 ((unsigned)rtn1(tile[2 * txk + 1][ny]) << 16);
    *(unsigned*)&dh[(size_t)(n0 + ny) * Kp + k0 + 2 * txk] = p;
  }
}

// ---------------------------------------------------------------------------
// 1-pass bf16 MFMA GEMM, double-buffered global_load_lds staging with
// counted vmcnt (prefetch stays in flight across barriers). XOR swizzle.
// A [M][lda] bf16, B [N][ldb] bf16 (transposed weights). C fp32 [M][ldc].
// K % 32 == 0, M % 128 == 0, N % 64 == 0. block = 256 thr = 4 waves;
// tile BM=128 x BN=64, wave tile 64x32, BK=32, LDS 2x12 KB.
// gridDim.z slices K (partials at C + z*M*ldc; caller reduces).
// EPI: 0 = store, 1 = softplus(c + bias[n])
template <int EPI>
__global__ __launch_bounds__(256) void gemm_bf16(
    const ushort* __restrict__ A, int lda, const ushort* __restrict__ B,
    int ldb, float* __restrict__ C, int ldc, int K,
    const float* __restrict__ bias) {
  __shared__ ushort lds[2][192 * 32];

  const int tid = threadIdx.x;
  const int bm = blockIdx.y * 128;
  const int bn = blockIdx.x * 64;
  const int kz0 = blockIdx.z * K;
  const int lane = tid & 63;
  const int wid = tid >> 6;
  const int wm = wid & 1, wn = wid >> 1;
  const int r = lane & 15, g = lane >> 4;
  const int segrow = lane >> 2;
  const int segch = lane & 3;

  auto stage = [&](int buf, int k0) {
#pragma unroll
    for (int i = 0; i < 3; i++) {
      int s = wid * 3 + i;
      int gr = s * 16 + segrow;
      int rt = gr & 63;
      int ch = segch ^ ((rt >> 1) & 3);
      bool isA = gr < 128;
      const ushort* src = isA ? A : B;
      int row = isA ? (bm + gr) : (bn + gr - 128);
      int ld = isA ? lda : ldb;
      gload16(src + (size_t)row * ld + k0 + ch * 8, &lds[buf][s * 512]);
    }
  };

  f32x4 acc[4][2] = {};
  const int nt = K / 32;

  stage(0, kz0);

  for (int t = 0; t < nt; t++) {
    const int cur = t & 1;
    if (t + 1 < nt) {
      stage(cur ^ 1, kz0 + (t + 1) * 32);
      asm volatile("s_waitcnt vmcnt(3)" ::: "memory");
    } else {
      asm volatile("s_waitcnt vmcnt(0)" ::: "memory");
    }
    __builtin_amdgcn_s_barrier();
    __builtin_amdgcn_sched_barrier(0);

    short8 af[4], bf[2];
#pragma unroll
    for (int m = 0; m < 4; m++) {
      int row = wm * 64 + m * 16 + r;
      int gg = g ^ ((row >> 1) & 3);
      af[m] = *reinterpret_cast<short8*>(&lds[cur][row * 32 + gg * 8]);
    }
#pragma unroll
    for (int n = 0; n < 2; n++) {
      int row = wn * 32 + n * 16 + r;
      int gg = g ^ ((row >> 1) & 3);
      bf[n] = *reinterpret_cast<short8*>(&lds[cur][(128 + row) * 32 + gg * 8]);
    }
#pragma unroll
    for (int m = 0; m < 4; m++)
#pragma unroll
      for (int n = 0; n < 2; n++)
        acc[m][n] = __builtin_amdgcn_mfma_f32_16x16x32_bf16(
            af[m], bf[n], acc[m][n], 0, 0, 0);
    __builtin_amdgcn_s_barrier();
  }

  float* Cz = C + (size_t)blockIdx.z * gridDim.y * 128 * ldc;
#pragma unroll
  for (int m = 0; m < 4; m++) {
#pragma unroll
    for (int n = 0; n < 2; n++) {
      int row0 = bm + wm * 64 + m * 16 + g * 4;
      int col = bn + wn * 32 + n * 16 + r;
#pragma unroll
      for (int j = 0; j < 4; j++) {
        size_t idx = (size_t)(row0 + j) * ldc + col;
        float v = acc[m][n][j];
        if (EPI == 0) {
          Cz[idx] = v;
        } else {
          v += bias[col];
          Cz[idx] = (v > 20.f) ? v : log1pf(__expf(v));
        }
      }
    }
  }
}

// ---------------------------------------------------------------------------
__global__ __launch_bounds__(256) void encode_k(
    const float* __restrict__ x, const float* __restrict__ w_enc,
    const float* __restrict__ b_enc, float* __restrict__ u) {
  int d = blockIdx.x * 256 + threadIdx.x;
  int t = blockIdx.y;
  const float4 xv = *(const float4*)(x + t * 4);
  float acc = b_enc[d];
  acc = fmaf(xv.x, w_enc[0 * D_MODEL + d], acc);
  acc = fmaf(xv.y, w_enc[1 * D_MODEL + d], acc);
  acc = fmaf(xv.z, w_enc[2 * D_MODEL + d], acc);
  acc = fmaf(xv.w, w_enc[3 * D_MODEL + d], acc);
  u[t * D_MODEL + d] = acc;
}

// ---------------------------------------------------------------------------
// layer-0 rmsnorm -> bf16
__global__ __launch_bounds__(256) void rmsnorm_b_k(
    const float* __restrict__ u, const float* __restrict__ w,
    ushort* __restrict__ hb) {
  int t = blockIdx.x;
  const float* ur = u + t * D_MODEL;
  float ss = 0.f;
  float vl[3];
#pragma unroll
  for (int p = 0; p < 3; p++) {
    int d = threadIdx.x + p * 256;
    vl[p] = ur[d];
    ss = fmaf(vl[p], vl[p], ss);
  }
#pragma unroll
  for (int o = 1; o < 64; o <<= 1) ss += __shfl_xor(ss, o);
  __shared__ float red[4];
  int wid = threadIdx.x >> 6;
  if ((threadIdx.x & 63) == 0) red[wid] = ss;
  __syncthreads();
  float rs = rsqrtf((red[0] + red[1] + red[2] + red[3]) / (float)D_MODEL +
                    1e-5f);
#pragma unroll
  for (int p = 0; p < 3; p++) {
    int d = threadIdx.x + p * 256;
    hb[t * D_MODEL + d] = rtn1(vl[p] * rs * w[d]);
  }
}

// rmsnorm fused with residual accumulation of prev layer's split-K partials
__global__ __launch_bounds__(256) void rmsnorm_add_k(
    const float* __restrict__ Po, float* __restrict__ u,
    const float* __restrict__ w, ushort* __restrict__ hb) {
  int t = blockIdx.x;
  float* ur = u + t * D_MODEL;
  float ss = 0.f;
  float vl[3];
#pragma unroll
  for (int p = 0; p < 3; p++) {
    int d = threadIdx.x + p * 256;
    float v = ur[d];
#pragma unroll
    for (int z = 0; z < KSPLIT_OUT; z++)
      v += Po[(size_t)z * L_SEQ * D_MODEL + (size_t)t * D_MODEL + d];
    ur[d] = v;
    vl[p] = v;
    ss = fmaf(v, v, ss);
  }
#pragma unroll
  for (int o = 1; o < 64; o <<= 1) ss += __shfl_xor(ss, o);
  __shared__ float red[4];
  int wid = threadIdx.x >> 6;
  if ((threadIdx.x & 63) == 0) red[wid] = ss;
  __syncthreads();
  float rs = rsqrtf((red[0] + red[1] + red[2] + red[3]) / (float)D_MODEL +
                    1e-5f);
#pragma unroll
  for (int p = 0; p < 3; p++) {
    int d = threadIdx.x + p * 256;
    hb[t * D_MODEL + d] = rtn1(vl[p] * rs * w[d]);
  }
}

// ---------------------------------------------------------------------------
// dbl GEMM (M=1024, N=80, K=1536) split-K fp32 partials, conv+silu fused
// into A-staging. T14 issue-early pipeline.
#define DBL_NS 8
#define DBL_KSEG (D_INNER / DBL_NS)  // 192
__global__ __launch_bounds__(256) void gemm_dblconv_k(
    const float* __restrict__ xz, const float* __restrict__ cw,
    const float* __restrict__ cb, const float* __restrict__ B,
    float* __restrict__ P, float* __restrict__ xc) {
  __shared__ float As2[16][17];
  __shared__ float Bs2[16][80];
  const int tid = threadIdx.x;
  const int bm = blockIdx.y * 16;
  const int ks0 = blockIdx.x * DBL_KSEG;
  const int tx = tid % 16;
  const int ty = tid / 16;
  const int sm = tid / 16, sk = tid % 16;
  const int t = bm + sm;

  float4 wv;
  float cbv, xv0, xv1, xv2, xv3, bv0, bv1, bv2, bv3, bv4;
  auto issue = [&](int k0) {
    int c = k0 + sk;
    wv = *(const float4*)(cw + c * 4);
    cbv = cb[c];
    xv0 = (t >= 3) ? xz[(size_t)(t - 3) * 2 * D_INNER + c] : 0.f;
    xv1 = (t >= 2) ? xz[(size_t)(t - 2) * 2 * D_INNER + c] : 0.f;
    xv2 = (t >= 1) ? xz[(size_t)(t - 1) * 2 * D_INNER + c] : 0.f;
    xv3 = xz[(size_t)t * 2 * D_INNER + c];
    bv0 = B[(size_t)(k0 + (tid + 0) / 80) * 80 + (tid + 0) % 80];
    bv1 = B[(size_t)(k0 + (tid + 256) / 80) * 80 + (tid + 256) % 80];
    bv2 = B[(size_t)(k0 + (tid + 512) / 80) * 80 + (tid + 512) % 80];
    bv3 = B[(size_t)(k0 + (tid + 768) / 80) * 80 + (tid + 768) % 80];
    bv4 = B[(size_t)(k0 + (tid + 1024) / 80) * 80 + (tid + 1024) % 80];
  };

  float acc[5] = {0.f, 0.f, 0.f, 0.f, 0.f};

  issue(ks0);

  for (int k0 = ks0; k0 < ks0 + DBL_KSEG; k0 += 16) {
    float a = cbv;
    a = fmaf(xv0, wv.x, a);
    a = fmaf(xv1, wv.y, a);
    a = fmaf(xv2, wv.z, a);
    a = fmaf(xv3, wv.w, a);
    float v = a / (1.f + __expf(-a));
    xc[(size_t)t * D_INNER + k0 + sk] = v;
    As2[sk][sm] = v;
    Bs2[(tid + 0) / 80][(tid + 0) % 80] = bv0;
    Bs2[(tid + 256) / 80][(tid + 256) % 80] = bv1;
    Bs2[(tid + 512) / 80][(tid + 512) % 80] = bv2;
    Bs2[(tid + 768) / 80][(tid + 768) % 80] = bv3;
    Bs2[(tid + 1024) / 80][(tid + 1024) % 80] = bv4;
    if (k0 + 16 < ks0 + DBL_KSEG) issue(k0 + 16);
    asm volatile("s_waitcnt lgkmcnt(0)" ::: "memory");
    __builtin_amdgcn_s_barrier();
    __builtin_amdgcn_sched_barrier(0);
#pragma unroll
    for (int k = 0; k < 16; k++) {
      float ra = As2[k][ty];
#pragma unroll
      for (int j = 0; j < 5; j++) acc[j] = fmaf(ra, Bs2[k][tx * 5 + j], acc[j]);
    }
    __builtin_amdgcn_s_barrier();
  }

  float* p = P + ((size_t)blockIdx.x * L_SEQ + bm + ty) * 80 + tx * 5;
#pragma unroll
  for (int j = 0; j < 5; j++) p[j] = acc[j];
}

// reduce + emit dt-GEMM A operand [1024][64] bf16 (cols 48..63 zero)
__global__ __launch_bounds__(256) void dbl_reduce_k(
    const float* __restrict__ P, float* __restrict__ dbl,
    ushort* __restrict__ dab) {
  int i = blockIdx.x * 256 + threadIdx.x;  // 0..81919
  float s = 0.f;
#pragma unroll
  for (int ks = 0; ks < DBL_NS; ks++) s += P[(size_t)ks * L_SEQ * 80 + i];
  dbl[i] = s;
  int rowi = i / 80, col = i % 80;
  if (col < DT_RANK) {
    dab[rowi * 64 + col] = rtn1(s);
  } else if (col >= 64) {  // cover pad cols 48..63
    dab[rowi * 64 + col - 16] = 0;
  }
}

// ---------------------------------------------------------------------------
// Chunked selective scan, NCHUNK=16 chunks of 64 steps; chunk combine
// folded into scan3.
__global__ __launch_bounds__(256) void scan1_k(
    const float* __restrict__ dt, const float* __restrict__ xc,
    const float* __restrict__ dbl, const float* __restrict__ A_log,
    float* __restrict__ Pb, float* __restrict__ Eb) {
  __shared__ float s_dt[CS][16];
  __shared__ float s_xc[CS][16];
  __shared__ float s_b[CS][16];
  const int tid = threadIdx.x;
  const int s = tid & 15;
  const int cl = tid >> 4;
  const int c0 = blockIdx.y * 16;
  const int c = c0 + cl;
  const int t0 = blockIdx.x * CS;
  const float a = -__expf(A_log[c * D_STATE + s]);

  const int lc = tid & 15, lt = tid >> 4;
#pragma unroll
  for (int p = 0; p < CS / 16; p++) {
    int t = lt + p * 16;
    size_t gt = (size_t)(t0 + t);
    s_dt[t][lc] = dt[gt * D_INNER + c0 + lc];
    s_xc[t][lc] = xc[gt * D_INNER + c0 + lc];
    s_b[t][lc] = dbl[gt * 80 + DT_RANK + lc];
  }
  __syncthreads();

  float P = 1.f, h = 0.f;
  for (int t = 0; t < CS; t++) {
    float dtv = s_dt[t][cl];
    float dA = __expf(dtv * a);
    P *= dA;
    h = fmaf(dA, h, dtv * s_b[t][s] * s_xc[t][cl]);
  }
  int idx = blockIdx.x * (D_INNER * D_STATE) + c0 * D_STATE + tid;
  Pb[idx] = P;
  Eb[idx] = h;
}

// phase 3 (+ inline chunk combine) -> y bf16 (RTN)
__global__ __launch_bounds__(256) void scan3_k(
    const float* __restrict__ dt, const float* __restrict__ xc,
    const float* __restrict__ dbl, const float* __restrict__ xz,
    const float* __restrict__ A_log, const float* __restrict__ D_skip,
    const float* __restrict__ Pb, const float* __restrict__ Eb,
    ushort* __restrict__ yb16) {
  __shared__ float s_dt[CS][16];
  __shared__ float s_xc[CS][16];
  __shared__ float s_z[CS][16];
  __shared__ float s_bc[CS][32];

  const int tid = threadIdx.x;
  const int s = tid & 15;
  const int cl = tid >> 4;
  const int c0 = blockIdx.y * 16;
  const int c = c0 + cl;
  const int t0 = blockIdx.x * CS;

  const float a = -__expf(A_log[c * D_STATE + s]);
  const float Dv = D_skip[c];

  const int lc = tid & 15, lt = tid >> 4;
  const int bj = tid & 31, bt = tid >> 5;
#pragma unroll
  for (int p = 0; p < CS / 16; p++) {
    int t = lt + p * 16;
    size_t gt = (size_t)(t0 + t);
    s_dt[t][lc] = dt[gt * D_INNER + c0 + lc];
    s_xc[t][lc] = xc[gt * D_INNER + c0 + lc];
    s_z[t][lc] = xz[gt * 2 * D_INNER + D_INNER + c0 + lc];
  }
#pragma unroll
  for (int p = 0; p < CS / 8; p++) {
    int t = bt + p * 8;
    s_bc[t][bj] = dbl[(size_t)(t0 + t) * 80 + DT_RANK + bj];
  }

  // inline chunk combine: start state for this chunk (static indices)
  float hst = 0.f;
  {
    const int nj = blockIdx.x;
    const int base = c0 * D_STATE + tid;
    float pj[NCHUNK - 1], ej[NCHUNK - 1];
#pragma unroll
    for (int jj = 0; jj < NCHUNK - 1; jj++) {
      if (jj < nj) {
        int o = jj * (D_INNER * D_STATE) + base;
        pj[jj] = Pb[o];
        ej[jj] = Eb[o];
      }
    }
#pragma unroll
    for (int jj = 0; jj < NCHUNK - 1; jj++)
      if (jj < nj) hst = fmaf(pj[jj], hst, ej[jj]);
  }
  __syncthreads();

  for (int t = 0; t < CS; t++) {
    float dtv = s_dt[t][cl];
    float xv = s_xc[t][cl];
    float Bv = s_bc[t][s];
    float Cv = s_bc[t][16 + s];
    float dA = __expf(dtv * a);
    hst = fmaf(dA, hst, dtv * Bv * xv);
    float p2 = hst * Cv;
    p2 += __shfl_xor(p2, 1);
    p2 += __shfl_xor(p2, 2);
    p2 += __shfl_xor(p2, 4);
    p2 += __shfl_xor(p2, 8);
    if (s == 0) {
      float zv = s_z[t][cl];
      float sz = zv / (1.f + __expf(-zv));
      yb16[(size_t)(t0 + t) * D_INNER + c] = rtn1((p2 + Dv * xv) * sz);
    }
  }
}

// ---------------------------------------------------------------------------
// final: u[1023] += sum_z Po[z][1023]; rmsnorm; @ fc_w + fc_b
__global__ __launch_bounds__(256) void final_k(
    const float* __restrict__ u, const float* __restrict__ Po,
    const float* __restrict__ nfw, const float* __restrict__ fcw,
    const float* __restrict__ fcb, float* __restrict__ out) {
  const float* ur = u + (size_t)(L_SEQ - 1) * D_MODEL;
  float ss = 0.f;
  float vl[3];
#pragma unroll
  for (int p = 0; p < 3; p++) {
    int d = threadIdx.x + p * 256;
    float v = ur[d];
#pragma unroll
    for (int z = 0; z < KSPLIT_OUT; z++)
      v += Po[(size_t)z * L_SEQ * D_MODEL + (size_t)(L_SEQ - 1) * D_MODEL + d];
    vl[p] = v;
    ss = fmaf(v, v, ss);
  }
#pragma unroll
  for (int o = 1; o < 64; o <<= 1) ss += __shfl_xor(ss, o);
  __shared__ float red[4];
  int wid = threadIdx.x >> 6;
  if ((threadIdx.x & 63) == 0) red[wid] = ss;
  __syncthreads();
  float rs = rsqrtf((red[0] + red[1] + red[2] + red[3]) / (float)D_MODEL +
                    1e-5f);
  float a0 = 0.f, a1 = 0.f;
#pragma unroll
  for (int p = 0; p < 3; p++) {
    int d = threadIdx.x + p * 256;
    float hn = vl[p] * rs * nfw[d];
    a0 = fmaf(hn, fcw[d * 2 + 0], a0);
    a1 = fmaf(hn, fcw[d * 2 + 1], a1);
  }
#pragma unroll
  for (int o = 1; o < 64; o <<= 1) {
    a0 += __shfl_xor(a0, o);
    a1 += __shfl_xor(a1, o);
  }
  __shared__ float r0[4], r1[4];
  if ((threadIdx.x & 63) == 0) {
    r0[wid] = a0;
    r1[wid] = a1;
  }
  __syncthreads();
  if (threadIdx.x == 0) out[0] = r0[0] + r0[1] + r0[2] + r0[3] + fcb[0];
  if (threadIdx.x == 1) out[1] = r1[0] + r1[1] + r1[2] + r1[3] + fcb[1];
}

// ---------------------------------------------------------------------------
extern "C" void kernel_launch(void* const* d_in, const int* in_sizes, int n_in,
                              void* d_out, int out_size, void* d_ws,
                              size_t ws_size, hipStream_t stream) {
  const float* x      = (const float*)d_in[0];
  const float* w_enc  = (const float*)d_in[1];
  const float* b_enc  = (const float*)d_in[2];
  const float* norm_w = (const float*)d_in[3];
  const float* in_w   = (const float*)d_in[4];
  const float* conv_w = (const float*)d_in[5];
  const float* conv_b = (const float*)d_in[6];
  const float* xp_w   = (const float*)d_in[7];
  const float* dt_w   = (const float*)d_in[8];
  const float* dt_b   = (const float*)d_in[9];
  const float* A_log  = (const float*)d_in[10];
  const float* D_skip = (const float*)d_in[11];
  const float* out_w  = (const float*)d_in[12];
  const float* nf_w   = (const float*)d_in[13];
  const float* fc_w   = (const float*)d_in[14];
  const float* fc_b   = (const float*)d_in[15];
  float* out = (float*)d_out;

  // ---- fp32 workspace
  float* u   = (float*)d_ws;
  float* xzb = u   + (size_t)L_SEQ * D_MODEL;
  float* xcb = xzb + (size_t)L_SEQ * 2 * D_INNER;
  float* dbl = xcb + (size_t)L_SEQ * D_INNER;
  float* dtb = dbl + (size_t)L_SEQ * 80;
  float* yb  = dtb + (size_t)L_SEQ * D_INNER;      // dbl split-K partials
  float* Po  = yb  + (size_t)L_SEQ * 80 * DBL_NS;  // out split-K partials x4
  float* Pb  = Po  + (size_t)KSPLIT_OUT * L_SEQ * D_MODEL;
  float* Eb  = Pb  + (size_t)NCHUNK * D_INNER * D_STATE;
  float* fend = Eb + (size_t)NCHUNK * D_INNER * D_STATE;

  // ---- bf16 workspace (activations + repacked weights)
  ushort* hb   = (ushort*)fend;                 // [1024][768]
  ushort* dab  = hb + (size_t)L_SEQ * D_MODEL;  // [1024][64]
  ushort* yb16 = dab + (size_t)L_SEQ * 64;      // [1024][1536]
  ushort* wxT  = yb16 + (size_t)L_SEQ * D_INNER;  // in_w^T  [24][3072][768]
  ushort* wdT  = wxT + (size_t)N_LAYERS * 2 * D_INNER * D_MODEL;  // [24][1536][64]
  ushort* woT  = wdT + (size_t)N_LAYERS * D_INNER * 64;  // [24][768][1536]

  // ---- one-time per call: weight repack (transpose + bf16 RTN)
  tsplit_k<<<dim3(2 * D_INNER / 64, D_MODEL / 64, N_LAYERS), 256, 0, stream>>>(
      in_w, wxT, D_MODEL, 2 * D_INNER, D_MODEL);
  tsplit_k<<<dim3(D_INNER / 64, 1, N_LAYERS), 256, 0, stream>>>(
      dt_w, wdT, DT_RANK, D_INNER, 64);
  tsplit_k<<<dim3(D_MODEL / 64, D_INNER / 64, N_LAYERS), 256, 0, stream>>>(
      out_w, woT, D_INNER, D_MODEL, D_INNER);

  encode_k<<<dim3(3, L_SEQ), 256, 0, stream>>>(x, w_enc, b_enc, u);

  for (int l = 0; l < N_LAYERS; l++) {
    const float* cw_l    = conv_w + (size_t)l * D_INNER * 4;
    const float* cb_l    = conv_b + (size_t)l * D_INNER;
    const float* xp_w_l  = xp_w  + (size_t)l * D_INNER * 80;
    const float* dt_b_l  = dt_b  + (size_t)l * D_INNER;
    const float* A_log_l = A_log + (size_t)l * D_INNER * D_STATE;
    const float* D_l     = D_skip + (size_t)l * D_INNER;
    const ushort* wxT_l = wxT + (size_t)l * 2 * D_INNER * D_MODEL;
    const ushort* wdT_l = wdT + (size_t)l * D_INNER * 64;
    const ushort* woT_l = woT + (size_t)l * D_MODEL * D_INNER;

    // h = bf16(rmsnorm(u [+ prev-layer out partials]) * norm_w)
    if (l == 0) {
      rmsnorm_b_k<<<L_SEQ, 256, 0, stream>>>(
          u, norm_w + (size_t)l * D_MODEL, hb);
    } else {
      rmsnorm_add_k<<<L_SEQ, 256, 0, stream>>>(
          Po, u, norm_w + (size_t)l * D_MODEL, hb);
    }
    // xz = h @ in_w : M=1024 N=3072 K=768 (384 blocks)
    gemm_bf16<0><<<dim3(2 * D_INNER / 64, L_SEQ / 128), 256, 0, stream>>>(
        hb, D_MODEL, wxT_l, D_MODEL, xzb, 2 * D_INNER, D_MODEL, nullptr);
    // xc = silu(conv(xpart)+cb) fused into dbl split-K GEMM (512 blocks)
    gemm_dblconv_k<<<dim3(DBL_NS, L_SEQ / 16), 256, 0, stream>>>(
        xzb, cw_l, cb_l, xp_w_l, yb, xcb);
    dbl_reduce_k<<<(L_SEQ * 80) / 256, 256, 0, stream>>>(yb, dbl, dab);
    // dt = softplus(dbl[:, :48] @ dt_w + dt_b) : K=48 padded to 64 (192 blk)
    gemm_bf16<1><<<dim3(D_INNER / 64, L_SEQ / 128), 256, 0, stream>>>(
        dab, 64, wdT_l, 64, dtb, D_INNER, 64, dt_b_l);
    // chunked selective scan + skip + silu(z) gate -> y bf16
    scan1_k<<<dim3(NCHUNK, D_INNER / 16), 256, 0, stream>>>(
        dtb, xcb, dbl, A_log_l, Pb, Eb);
    scan3_k<<<dim3(NCHUNK, D_INNER / 16), 256, 0, stream>>>(
        dtb, xcb, dbl, xzb, A_log_l, D_l, Pb, Eb, yb16);
    // Po[z] = y @ out_w slices : M=1024 N=768, split-K x4 (384 blocks)
    gemm_bf16<0><<<dim3(D_MODEL / 64, L_SEQ / 128, KSPLIT_OUT), 256, 0,
                   stream>>>(yb16, D_INNER, woT_l, D_INNER, Po, D_MODEL,
                             D_INNER / KSPLIT_OUT, nullptr);
    // u-update deferred into next layer's rmsnorm_add / final_k
  }

  final_k<<<1, 256, 0, stream>>>(u, Po, nf_w, fc_w, fc_b, out);
}